// Round 1
// baseline (11241.289 us; speedup 1.0000x reference)
//
#include <hip/hip_runtime.h>

typedef __attribute__((ext_vector_type(8))) short bf16x8;
typedef __attribute__((ext_vector_type(4))) float f32x4;

union U16 { uint4 u; bf16x8 v; };

__device__ inline unsigned short f2bf(float f) {
    unsigned int u = __float_as_uint(f);
    unsigned int r = (u + 0x7FFFu + ((u >> 16) & 1u)) >> 16;
    return (unsigned short)r;
}

// tanh via hardware exp + rcp; ~1e-6 abs accuracy, well below bf16 noise.
__device__ inline float tanh_fast(float x) {
    float xc = fminf(8.f, fmaxf(-8.f, x));
    float e  = __expf(xc + xc);           // e^{2x}
    return (e - 1.f) * __builtin_amdgcn_rcpf(e + 1.f);
}

#define T_STEPS 1000

// Block: 256 threads (4 waves), owns 16 batch rows for the whole rollout.
// Per eval: h1 = tanh(y@W1+b1) in fp32 VALU -> LDS (bf16, XOR-swizzled);
// h2pre = W2^T · h1^T via mfma_f32_16x16x32_bf16 (swapped so lane's col = batch);
// tanh + W3 partials in fp32; shfl_xor + LDS reduce -> k; wave0 does RK4.
__global__ __launch_bounds__(256, 2)
void node_ode_kernel(const float* __restrict__ Ig, const float* __restrict__ tg,
                     const float* __restrict__ W1g, const float* __restrict__ b1g,
                     const float* __restrict__ W2g, const float* __restrict__ b2g,
                     const float* __restrict__ W3g, const float* __restrict__ b3g,
                     float* __restrict__ outp)
{
    __shared__ uint4 h1s[16 * 32];     // 16 rows x 32 16B-granules (bf16, swizzled)
    __shared__ float w1s[3 * 256];
    __shared__ float b1s[256];
    __shared__ float b2s[256];
    __shared__ float w3s[256 * 3];
    __shared__ float part[4][16][3];
    __shared__ float y0s[48], ycs[48], kss[48];

    const int tid  = threadIdx.x;
    const int lane = tid & 63;
    const int wv   = tid >> 6;
    const int nb   = lane & 15;        // batch row within tile (= MFMA lane&15 index)
    const int g4   = lane >> 4;        // lane group 0..3
    const int widx = wv * 4 + g4;      // 0..15: h1-compute column-range owner
    const int c0   = widx * 16;
    const int xm   = nb & 7;           // LDS granule XOR swizzle key
    const int bb0  = blockIdx.x * 16;  // first global batch row of this block

    // ---- stage small weights to LDS; init state; write t=0 output ----
    for (int i = tid; i < 768; i += 256) { w1s[i] = W1g[i]; w3s[i] = W3g[i]; }
    b1s[tid] = b1g[tid];
    b2s[tid] = b2g[tid];
    if (tid < 48) {
        float v = Ig[bb0 * 3 + tid];
        y0s[tid] = v; ycs[tid] = v;
        outp[(size_t)(bb0 + tid / 3) * (T_STEPS * 3) + (tid % 3)] = v;
    }

    // ---- W2 -> persistent bf16 A-fragments in VGPRs (W2^T tiles) ----
    // A-frag(16x16x32): lane holds A[m = lane&15][k = 8*(lane>>4)+j], j=0..7.
    // A = W2^T tile: m -> ncol = wv*64 + mt*16 + (lane&15); k -> W2 row.
    bf16x8 w2f[4][8];
    {
        const int ncb = wv * 64 + nb;
        #pragma unroll
        for (int mt = 0; mt < 4; ++mt) {
            #pragma unroll
            for (int ks = 0; ks < 8; ++ks) {
                uint pk[4];
                #pragma unroll
                for (int jj = 0; jj < 4; ++jj) {
                    int k0 = ks * 32 + g4 * 8 + jj * 2;
                    unsigned int lo16 = f2bf(W2g[(size_t)k0 * 256 + ncb + mt * 16]);
                    unsigned int hi16 = f2bf(W2g[(size_t)(k0 + 1) * 256 + ncb + mt * 16]);
                    pk[jj] = lo16 | (hi16 << 16);
                }
                U16 tmpu; tmpu.u = make_uint4(pk[0], pk[1], pk[2], pk[3]);
                w2f[mt][ks] = tmpu.v;
            }
        }
    }

    __syncthreads();

    for (int t = 0; t < T_STEPS - 1; ++t) {
        for (int e = 0; e < 4; ++e) {
            // ---- stage A: h1 = tanh(y @ W1 + b1); bf16 -> swizzled LDS ----
            {
                float s0 = ycs[nb * 3 + 0], s1 = ycs[nb * 3 + 1], s2 = ycs[nb * 3 + 2];
                unsigned short hb[16];
                #pragma unroll
                for (int q = 0; q < 4; ++q) {
                    int c = c0 + q * 4;
                    float4 a0 = *(const float4*)&w1s[c];
                    float4 a1 = *(const float4*)&w1s[256 + c];
                    float4 a2 = *(const float4*)&w1s[512 + c];
                    float4 bv = *(const float4*)&b1s[c];
                    hb[q*4+0] = f2bf(tanh_fast(bv.x + s0*a0.x + s1*a1.x + s2*a2.x));
                    hb[q*4+1] = f2bf(tanh_fast(bv.y + s0*a0.y + s1*a1.y + s2*a2.y));
                    hb[q*4+2] = f2bf(tanh_fast(bv.z + s0*a0.z + s1*a1.z + s2*a2.z));
                    hb[q*4+3] = f2bf(tanh_fast(bv.w + s0*a0.w + s1*a1.w + s2*a2.w));
                }
                uint4 q0, q1;
                q0.x = (uint)hb[0]  | ((uint)hb[1]  << 16);
                q0.y = (uint)hb[2]  | ((uint)hb[3]  << 16);
                q0.z = (uint)hb[4]  | ((uint)hb[5]  << 16);
                q0.w = (uint)hb[6]  | ((uint)hb[7]  << 16);
                q1.x = (uint)hb[8]  | ((uint)hb[9]  << 16);
                q1.y = (uint)hb[10] | ((uint)hb[11] << 16);
                q1.z = (uint)hb[12] | ((uint)hb[13] << 16);
                q1.w = (uint)hb[14] | ((uint)hb[15] << 16);
                h1s[nb * 32 + ((widx * 2 + 0) ^ xm)] = q0;
                h1s[nb * 32 + ((widx * 2 + 1) ^ xm)] = q1;
            }
            __syncthreads();

            // ---- stage B: MFMA h2pre = W2^T·h1^T + b2; tanh; W3 partials ----
            {
                // B-frag: lane holds B[k = 8*(lane>>4)+j][n = lane&15] = h1[nb][k_global]
                bf16x8 hf[8];
                #pragma unroll
                for (int ks = 0; ks < 8; ++ks) {
                    U16 tmpu; tmpu.u = h1s[nb * 32 + ((ks * 4 + g4) ^ xm)];
                    hf[ks] = tmpu.v;
                }
                // C/D: acc[mt][r] = h2pre[ncol = wv*64+mt*16+4*g4+r][batch nb]
                f32x4 acc[4];
                #pragma unroll
                for (int mt = 0; mt < 4; ++mt) {
                    float4 bv = *(const float4*)&b2s[wv * 64 + mt * 16 + g4 * 4];
                    acc[mt][0] = bv.x; acc[mt][1] = bv.y; acc[mt][2] = bv.z; acc[mt][3] = bv.w;
                }
                #pragma unroll
                for (int ks = 0; ks < 8; ++ks) {
                    #pragma unroll
                    for (int mt = 0; mt < 4; ++mt)
                        acc[mt] = __builtin_amdgcn_mfma_f32_16x16x32_bf16(
                            w2f[mt][ks], hf[ks], acc[mt], 0, 0, 0);
                }
                float p0 = 0.f, p1 = 0.f, p2 = 0.f;
                #pragma unroll
                for (int mt = 0; mt < 4; ++mt) {
                    int row0 = wv * 64 + mt * 16 + g4 * 4;
                    float4 wa = *(const float4*)&w3s[row0 * 3];
                    float4 wb = *(const float4*)&w3s[row0 * 3 + 4];
                    float4 wc = *(const float4*)&w3s[row0 * 3 + 8];
                    float h;
                    h = tanh_fast(acc[mt][0]); p0 += h*wa.x; p1 += h*wa.y; p2 += h*wa.z;
                    h = tanh_fast(acc[mt][1]); p0 += h*wa.w; p1 += h*wb.x; p2 += h*wb.y;
                    h = tanh_fast(acc[mt][2]); p0 += h*wb.z; p1 += h*wb.w; p2 += h*wc.x;
                    h = tanh_fast(acc[mt][3]); p0 += h*wc.y; p1 += h*wc.z; p2 += h*wc.w;
                }
                p0 += __shfl_xor(p0, 16); p1 += __shfl_xor(p1, 16); p2 += __shfl_xor(p2, 16);
                p0 += __shfl_xor(p0, 32); p1 += __shfl_xor(p1, 32); p2 += __shfl_xor(p2, 32);
                if (lane < 16) {
                    part[wv][lane][0] = p0; part[wv][lane][1] = p1; part[wv][lane][2] = p2;
                }
            }
            __syncthreads();

            // ---- stage C: combine k; RK4 bookkeeping (wave 0, 48 threads) ----
            if (tid < 48) {
                const int d = tid % 3;
                const int r = tid / 3;
                float k = part[0][r][d] + part[1][r][d] + part[2][r][d] + part[3][r][d]
                          + b3g[d];
                float dtv = tg[t + 1] - tg[t];
                if (e == 0)      { kss[tid] = k;          ycs[tid] = y0s[tid] + 0.5f * dtv * k; }
                else if (e == 1) { kss[tid] += 2.f * k;   ycs[tid] = y0s[tid] + 0.5f * dtv * k; }
                else if (e == 2) { kss[tid] += 2.f * k;   ycs[tid] = y0s[tid] + dtv * k; }
                else {
                    float yn = y0s[tid] + (dtv * (1.f / 6.f)) * (kss[tid] + k);
                    y0s[tid] = yn; ycs[tid] = yn;
                    outp[(size_t)(bb0 + r) * (T_STEPS * 3) + (size_t)(t + 1) * 3 + d] = yn;
                }
            }
            __syncthreads();
        }
    }
}

extern "C" void kernel_launch(void* const* d_in, const int* in_sizes, int n_in,
                              void* d_out, int out_size, void* d_ws, size_t ws_size,
                              hipStream_t stream) {
    (void)in_sizes; (void)n_in; (void)d_ws; (void)ws_size; (void)out_size;
    const float* Ig  = (const float*)d_in[0];
    const float* tg  = (const float*)d_in[1];
    const float* W1g = (const float*)d_in[2];
    const float* b1g = (const float*)d_in[3];
    const float* W2g = (const float*)d_in[4];
    const float* b2g = (const float*)d_in[5];
    const float* W3g = (const float*)d_in[6];
    const float* b3g = (const float*)d_in[7];
    float* outp = (float*)d_out;

    dim3 grid(512), block(256);
    hipLaunchKernelGGL(node_ode_kernel, grid, block, 0, stream,
                       Ig, tg, W1g, b1g, W2g, b2g, W3g, b3g, outp);
}

// Round 2
// 8159.422 us; speedup vs baseline: 1.3777x; 1.3777x over previous
//
#include <hip/hip_runtime.h>

typedef __attribute__((ext_vector_type(8))) short bf16x8;
typedef __attribute__((ext_vector_type(4))) float f32x4;

union FU { unsigned int u[4]; uint4 q; bf16x8 v; };

__device__ inline unsigned int cvt_pk(float lo, float hi) {
    unsigned int r;
    asm("v_cvt_pk_bf16_f32 %0, %1, %2" : "=v"(r) : "v"(lo), "v"(hi));
    return r;
}

// tanh(x) = 1 - 2/(e^{2x}+1); inf/underflow saturate to +-1 correctly.
__device__ inline float tanh_fast(float x) {
    float e = __expf(x + x);
    return fmaf(-2.f, __builtin_amdgcn_rcpf(e + 1.f), 1.f);
}

#define TS 1000
#define NEV ((TS - 1) * 4)

// 512 threads = 8 waves own 16 batch rows for the whole rollout.
// Per eval: [combine prev k from part2, update y state in regs]
//           [stage A: h1 = tanh(W1aug @ [yh;yl;1]) via 2 mfma -> LDS bf16]
//           barrier
//           [stage B: h2pre = W2^T.h1^T + b2 via 16 mfma; tanh; W3 partials]
//           barrier
__global__ __launch_bounds__(512, 4)
void node_ode_kernel(const float* __restrict__ Ig, const float* __restrict__ tg,
                     const float* __restrict__ W1g, const float* __restrict__ b1g,
                     const float* __restrict__ W2g, const float* __restrict__ b2g,
                     const float* __restrict__ W3g, const float* __restrict__ b3g,
                     float* __restrict__ outp)
{
    __shared__ uint4 h1s[16 * 32];                 // 8 KiB: 16 rows x 32 octets
    __shared__ float w3s[256 * 3];                 // 3 KiB
    __shared__ __align__(16) float part2[16][28];  // row stride 112B (16B-mult)

    const int tid  = threadIdx.x;
    const int lane = tid & 63;
    const int wv   = tid >> 6;       // 0..7
    const int nb   = lane & 15;      // batch row in tile
    const int g4   = lane >> 4;      // 0..3
    const int xm   = nb & 7;         // LDS octet swizzle key
    const int bb0  = blockIdx.x * 16;

    for (int i = tid; i < 768; i += 512) w3s[i] = W3g[i];

    const float b30 = b3g[0], b31 = b3g[1], b32 = b3g[2];
    float4 b2r0 = *(const float4*)&b2g[wv * 32 + g4 * 4];
    float4 b2r1 = *(const float4*)&b2g[wv * 32 + 16 + g4 * 4];

    // ---- per-thread RK4 state (redundant across the 32 threads sharing nb) ----
    float y00 = Ig[(bb0 + nb) * 3 + 0];
    float y01 = Ig[(bb0 + nb) * 3 + 1];
    float y02 = Ig[(bb0 + nb) * 3 + 2];
    float yc0 = y00, yc1 = y01, yc2 = y02;
    float ks0 = 0.f, ks1 = 0.f, ks2 = 0.f;
    if (tid < 16) {
        size_t o = (size_t)(bb0 + tid) * (TS * 3);
        outp[o + 0] = y00; outp[o + 1] = y01; outp[o + 2] = y02;
    }

    // ---- W2 persistent A-frags: A[m=ncol][k=h1col], swapped GEMM ----
    bf16x8 w2f[2][8];
    {
        const int ncb = wv * 32 + nb;
        #pragma unroll
        for (int mt = 0; mt < 2; ++mt) {
            #pragma unroll
            for (int ks = 0; ks < 8; ++ks) {
                FU f;
                #pragma unroll
                for (int jj = 0; jj < 4; ++jj) {
                    int k0 = ks * 32 + g4 * 8 + jj * 2;
                    f.u[jj] = cvt_pk(W2g[(size_t)k0 * 256 + ncb + mt * 16],
                                     W2g[(size_t)(k0 + 1) * 256 + ncb + mt * 16]);
                }
                w2f[mt][ks] = f.v;
            }
        }
    }

    // ---- W1 persistent A-frags, split precision + bias:
    //      k=0..2 W1h, k=3..5 W1h, k=6 b1 (g4==0);  k=8..10 W1l (g4==1) ----
    bf16x8 w1a[2];
    {
        #pragma unroll
        for (int mt = 0; mt < 2; ++mt) {
            const int col = (wv * 2 + mt) * 16 + nb;
            float w0 = W1g[col], w1 = W1g[256 + col], w2 = W1g[512 + col];
            float bb = b1g[col];
            FU f;
            if (g4 == 0) {
                f.u[0] = cvt_pk(w0, w1);
                f.u[1] = cvt_pk(w2, w0);
                f.u[2] = cvt_pk(w1, w2);
                f.u[3] = cvt_pk(bb, 0.f);
            } else if (g4 == 1) {
                unsigned int p01 = cvt_pk(w0, w1);
                unsigned int p2x = cvt_pk(w2, 0.f);
                float w0l = w0 - __uint_as_float(p01 << 16);
                float w1l = w1 - __uint_as_float(p01 & 0xFFFF0000u);
                float w2l = w2 - __uint_as_float(p2x << 16);
                f.u[0] = cvt_pk(w0l, w1l);
                f.u[1] = cvt_pk(w2l, 0.f);
                f.u[2] = 0u; f.u[3] = 0u;
            } else {
                f.u[0] = f.u[1] = f.u[2] = f.u[3] = 0u;
            }
            w1a[mt] = f.v;
        }
    }
    __syncthreads();

    float dtv = tg[1] - tg[0];

    for (int ev = 0; ev < NEV; ++ev) {
        // ---- combine previous eval's k; advance RK4 state ----
        if (ev > 0) {
            float k0, k1, k2;
            {
                float4 a = *(const float4*)&part2[nb][0];
                float4 b = *(const float4*)&part2[nb][4];
                k0 = (((a.x + a.y) + (a.z + a.w)) + ((b.x + b.y) + (b.z + b.w))) + b30;
                a = *(const float4*)&part2[nb][8];
                b = *(const float4*)&part2[nb][12];
                k1 = (((a.x + a.y) + (a.z + a.w)) + ((b.x + b.y) + (b.z + b.w))) + b31;
                a = *(const float4*)&part2[nb][16];
                b = *(const float4*)&part2[nb][20];
                k2 = (((a.x + a.y) + (a.z + a.w)) + ((b.x + b.y) + (b.z + b.w))) + b32;
            }
            const int pph = (ev - 1) & 3;
            if (pph == 0) {
                ks0 = k0; ks1 = k1; ks2 = k2;
                float h = 0.5f * dtv;
                yc0 = fmaf(h, k0, y00); yc1 = fmaf(h, k1, y01); yc2 = fmaf(h, k2, y02);
            } else if (pph == 1) {
                ks0 += 2.f * k0; ks1 += 2.f * k1; ks2 += 2.f * k2;
                float h = 0.5f * dtv;
                yc0 = fmaf(h, k0, y00); yc1 = fmaf(h, k1, y01); yc2 = fmaf(h, k2, y02);
            } else if (pph == 2) {
                ks0 += 2.f * k0; ks1 += 2.f * k1; ks2 += 2.f * k2;
                yc0 = fmaf(dtv, k0, y00); yc1 = fmaf(dtv, k1, y01); yc2 = fmaf(dtv, k2, y02);
            } else {
                float s = dtv * (1.f / 6.f);
                y00 = fmaf(s, ks0 + k0, y00);
                y01 = fmaf(s, ks1 + k1, y01);
                y02 = fmaf(s, ks2 + k2, y02);
                yc0 = y00; yc1 = y01; yc2 = y02;
                const int t = ev >> 2;
                if (tid < 16) {
                    size_t o = (size_t)(bb0 + nb) * (TS * 3) + (size_t)t * 3;
                    outp[o + 0] = y00; outp[o + 1] = y01; outp[o + 2] = y02;
                }
                dtv = tg[t + 1] - tg[t];
            }
        }

        // ---- stage A: h1 via split-precision mfma; bf16 -> swizzled LDS ----
        {
            unsigned int u01  = cvt_pk(yc0, yc1);
            float yl0 = yc0 - __uint_as_float(u01 << 16);
            float yl1 = yc1 - __uint_as_float(u01 & 0xFFFF0000u);
            unsigned int u2l0 = cvt_pk(yc2, yl0);
            float yl2 = yc2 - __uint_as_float(u2l0 << 16);
            unsigned int ull  = cvt_pk(yl1, yl2);
            FU bf;
            if (g4 == 0) {
                bf.u[0] = u01; bf.u[1] = u2l0; bf.u[2] = ull; bf.u[3] = 0x00003f80u;
            } else if (g4 == 1) {
                bf.u[0] = u01; bf.u[1] = u2l0 & 0x0000FFFFu; bf.u[2] = 0u; bf.u[3] = 0u;
            } else {
                bf.u[0] = bf.u[1] = bf.u[2] = bf.u[3] = 0u;
            }
            #pragma unroll
            for (int mt = 0; mt < 2; ++mt) {
                f32x4 d = {0.f, 0.f, 0.f, 0.f};
                d = __builtin_amdgcn_mfma_f32_16x16x32_bf16(w1a[mt], bf.v, d, 0, 0, 0);
                float h0 = tanh_fast(d[0]);
                float h1 = tanh_fast(d[1]);
                float h2 = tanh_fast(d[2]);
                float h3 = tanh_fast(d[3]);
                uint2 wq;
                wq.x = cvt_pk(h0, h1);
                wq.y = cvt_pk(h2, h3);
                const int o = (wv * 2 + mt) * 2 + (g4 >> 1);
                *(uint2*)((char*)h1s + nb * 512 + ((o ^ xm) * 16) + ((g4 & 1) * 8)) = wq;
            }
        }
        __syncthreads();

        // ---- stage B: W2 mfma + tanh + W3 partials ----
        {
            f32x4 acc0, acc1;
            acc0[0] = b2r0.x; acc0[1] = b2r0.y; acc0[2] = b2r0.z; acc0[3] = b2r0.w;
            acc1[0] = b2r1.x; acc1[1] = b2r1.y; acc1[2] = b2r1.z; acc1[3] = b2r1.w;
            #pragma unroll
            for (int ks = 0; ks < 8; ++ks) {
                FU tm; tm.q = h1s[nb * 32 + ((ks * 4 + g4) ^ xm)];
                acc0 = __builtin_amdgcn_mfma_f32_16x16x32_bf16(w2f[0][ks], tm.v, acc0, 0, 0, 0);
                acc1 = __builtin_amdgcn_mfma_f32_16x16x32_bf16(w2f[1][ks], tm.v, acc1, 0, 0, 0);
            }
            float p0 = 0.f, p1 = 0.f, p2 = 0.f;
            {
                const int row0 = wv * 32 + g4 * 4;
                float4 wa = *(const float4*)&w3s[row0 * 3];
                float4 wb = *(const float4*)&w3s[row0 * 3 + 4];
                float4 wc = *(const float4*)&w3s[row0 * 3 + 8];
                float h;
                h = tanh_fast(acc0[0]); p0 = fmaf(h, wa.x, p0); p1 = fmaf(h, wa.y, p1); p2 = fmaf(h, wa.z, p2);
                h = tanh_fast(acc0[1]); p0 = fmaf(h, wa.w, p0); p1 = fmaf(h, wb.x, p1); p2 = fmaf(h, wb.y, p2);
                h = tanh_fast(acc0[2]); p0 = fmaf(h, wb.z, p0); p1 = fmaf(h, wb.w, p1); p2 = fmaf(h, wc.x, p2);
                h = tanh_fast(acc0[3]); p0 = fmaf(h, wc.y, p0); p1 = fmaf(h, wc.z, p1); p2 = fmaf(h, wc.w, p2);
            }
            {
                const int row0 = wv * 32 + 16 + g4 * 4;
                float4 wa = *(const float4*)&w3s[row0 * 3];
                float4 wb = *(const float4*)&w3s[row0 * 3 + 4];
                float4 wc = *(const float4*)&w3s[row0 * 3 + 8];
                float h;
                h = tanh_fast(acc1[0]); p0 = fmaf(h, wa.x, p0); p1 = fmaf(h, wa.y, p1); p2 = fmaf(h, wa.z, p2);
                h = tanh_fast(acc1[1]); p0 = fmaf(h, wa.w, p0); p1 = fmaf(h, wb.x, p1); p2 = fmaf(h, wb.y, p2);
                h = tanh_fast(acc1[2]); p0 = fmaf(h, wb.z, p0); p1 = fmaf(h, wb.w, p1); p2 = fmaf(h, wc.x, p2);
                h = tanh_fast(acc1[3]); p0 = fmaf(h, wc.y, p0); p1 = fmaf(h, wc.z, p1); p2 = fmaf(h, wc.w, p2);
            }
            p0 += __shfl_xor(p0, 16); p1 += __shfl_xor(p1, 16); p2 += __shfl_xor(p2, 16);
            p0 += __shfl_xor(p0, 32); p1 += __shfl_xor(p1, 32); p2 += __shfl_xor(p2, 32);
            if (lane < 16) {
                part2[lane][wv]      = p0;
                part2[lane][8 + wv]  = p1;
                part2[lane][16 + wv] = p2;
            }
        }
        __syncthreads();
    }

    // ---- tail: final k4 combine, write t = TS-1 ----
    {
        float4 a = *(const float4*)&part2[nb][0];
        float4 b = *(const float4*)&part2[nb][4];
        float k0 = (((a.x + a.y) + (a.z + a.w)) + ((b.x + b.y) + (b.z + b.w))) + b30;
        a = *(const float4*)&part2[nb][8];
        b = *(const float4*)&part2[nb][12];
        float k1 = (((a.x + a.y) + (a.z + a.w)) + ((b.x + b.y) + (b.z + b.w))) + b31;
        a = *(const float4*)&part2[nb][16];
        b = *(const float4*)&part2[nb][20];
        float k2 = (((a.x + a.y) + (a.z + a.w)) + ((b.x + b.y) + (b.z + b.w))) + b32;
        float s = dtv * (1.f / 6.f);
        y00 = fmaf(s, ks0 + k0, y00);
        y01 = fmaf(s, ks1 + k1, y01);
        y02 = fmaf(s, ks2 + k2, y02);
        if (tid < 16) {
            size_t o = (size_t)(bb0 + nb) * (TS * 3) + (size_t)(TS - 1) * 3;
            outp[o + 0] = y00; outp[o + 1] = y01; outp[o + 2] = y02;
        }
    }
}

extern "C" void kernel_launch(void* const* d_in, const int* in_sizes, int n_in,
                              void* d_out, int out_size, void* d_ws, size_t ws_size,
                              hipStream_t stream) {
    (void)in_sizes; (void)n_in; (void)d_ws; (void)ws_size; (void)out_size;
    const float* Ig  = (const float*)d_in[0];
    const float* tg  = (const float*)d_in[1];
    const float* W1g = (const float*)d_in[2];
    const float* b1g = (const float*)d_in[3];
    const float* W2g = (const float*)d_in[4];
    const float* b2g = (const float*)d_in[5];
    const float* W3g = (const float*)d_in[6];
    const float* b3g = (const float*)d_in[7];
    float* outp = (float*)d_out;

    dim3 grid(512), block(512);
    hipLaunchKernelGGL(node_ode_kernel, grid, block, 0, stream,
                       Ig, tg, W1g, b1g, W2g, b2g, W3g, b3g, outp);
}